// Round 1
// baseline (432.716 us; speedup 1.0000x reference)
//
#include <hip/hip_runtime.h>
#include <hip/hip_bf16.h>

#define B_ 16
#define S_ 1024
#define L_ 2048
#define H_ 32

static __device__ __forceinline__ float sigm(float v) {
    // 1/(1+e^-v) via native exp + rcp (errors ~1e-6, tolerance is 4e-3)
    return __builtin_amdgcn_rcpf(1.0f + __expf(-v));
}

// ---------------- block reductions (256 threads = 4 waves) ----------------
static __device__ __forceinline__ float block_red_max(float v, float* buf, int tid) {
#pragma unroll
    for (int o = 32; o; o >>= 1) v = fmaxf(v, __shfl_down(v, o));
    if ((tid & 63) == 0) buf[tid >> 6] = v;
    __syncthreads();
    v = fmaxf(fmaxf(buf[0], buf[1]), fmaxf(buf[2], buf[3]));
    __syncthreads();
    return v;
}
static __device__ __forceinline__ float block_red_sum(float v, float* buf, int tid) {
#pragma unroll
    for (int o = 32; o; o >>= 1) v += __shfl_down(v, o);
    if ((tid & 63) == 0) buf[tid >> 6] = v;
    __syncthreads();
    v = buf[0] + buf[1] + buf[2] + buf[3];
    __syncthreads();
    return v;
}

// ---------------- attention: softmax over keys is i-independent ----------------
// A[sel][b][d] = sum_j softmax_j(key[b,j]·wk) * value[b,j,d]
__global__ __launch_bounds__(256) void attn_kernel(
    const float* __restrict__ v1, const float* __restrict__ v2,
    const float* __restrict__ attn_w, float* __restrict__ A)
{
    const int b   = blockIdx.x & 15;
    const int sel = blockIdx.x >> 4;
    const float* v = (sel ? v2 : v1) + (size_t)b * ((L_ + 1) * 3);
    const float wk0 = attn_w[3], wk1 = attn_w[4], wk2 = attn_w[5];
    const int tid = threadIdx.x;
    __shared__ float buf[4];

    float s[8];
    float mx = -3.4e38f;
#pragma unroll
    for (int k = 0; k < 8; ++k) {
        int jj = tid + (k << 8);            // 0..2047 (key rows 0..L-1)
        const float* p = v + jj * 3;
        float sc = fmaf(p[2], wk2, fmaf(p[1], wk1, p[0] * wk0));
        s[k] = sc;
        mx = fmaxf(mx, sc);
    }
    mx = block_red_max(mx, buf, tid);

    float den = 0.f, a0 = 0.f, a1 = 0.f, a2 = 0.f;
#pragma unroll
    for (int k = 0; k < 8; ++k) {
        int jj = tid + (k << 8);
        float e = __expf(s[k] - mx);
        den += e;
        const float* p = v + (jj + 1) * 3;  // value rows 1..L
        a0 = fmaf(e, p[0], a0);
        a1 = fmaf(e, p[1], a1);
        a2 = fmaf(e, p[2], a2);
    }
    den = block_red_sum(den, buf, tid);
    a0  = block_red_sum(a0,  buf, tid);
    a1  = block_red_sum(a1,  buf, tid);
    a2  = block_red_sum(a2,  buf, tid);
    if (tid == 0) {
        float inv = 1.0f / den;
        float* dst = A + sel * 48 + b * 3;
        dst[0] = a0 * inv; dst[1] = a1 * inv; dst[2] = a2 * inv;
    }
}

// ---------------- LSTM scan: 1 batch per 64-lane wave ----------------
// lane l: j = l&31, hi = l>>5.  hi=0 -> rows (i_j, g_j); hi=1 -> rows (f_j, o_j)
__global__ __launch_bounds__(64) void lstm_kernel(
    const float* __restrict__ x,      // (16,1024,3)
    const float* __restrict__ fc1_w,  // (16,3)
    const float* __restrict__ fc1_b,  // (16,)
    const float* __restrict__ w_ih,   // (128,16)
    const float* __restrict__ w_hh,   // (128,32)
    const float* __restrict__ b_ih,   // (128,)
    const float* __restrict__ b_hh,   // (128,)
    float* __restrict__ h_out)        // (16,1024,32)
{
    const int b  = blockIdx.x;
    const int l  = threadIdx.x;
    const int j  = l & 31;
    const int hi = l >> 5;
    const int r0 = hi ? (32 + j) : j;          // f : i
    const int r1 = hi ? (96 + j) : (64 + j);   // o : g

    __shared__ float lds_x[S_ * 3];
    __shared__ float lds_h[64];                // double-buffered h

    // stage x[b] (12 KiB) into LDS
    {
        const float4* src = (const float4*)(x + (size_t)b * (S_ * 3));
        float4* dst = (float4*)lds_x;
#pragma unroll
        for (int m = 0; m < 12; ++m) dst[l + 64 * m] = src[l + 64 * m];
    }
    if (l < 32) lds_h[l] = 0.f;                // buffer 0 = h_{-1} = 0

    // per-lane recurrent weight rows in VGPRs
    float wh0[H_], wh1[H_];
    {
        const float4* p0 = (const float4*)(w_hh + r0 * H_);
        const float4* p1 = (const float4*)(w_hh + r1 * H_);
#pragma unroll
        for (int m = 0; m < 8; ++m) {
            float4 a = p0[m];
            wh0[4*m] = a.x; wh0[4*m+1] = a.y; wh0[4*m+2] = a.z; wh0[4*m+3] = a.w;
            float4 c2 = p1[m];
            wh1[4*m] = c2.x; wh1[4*m+1] = c2.y; wh1[4*m+2] = c2.z; wh1[4*m+3] = c2.w;
        }
    }
    // fold fc1 into the input path: W = w_ih@fc1_w (row), bb = w_ih@fc1_b + b_ih + b_hh
    float W00 = 0, W01 = 0, W02 = 0, W10 = 0, W11 = 0, W12 = 0, bb0, bb1;
    {
        float s0 = 0, s1 = 0;
#pragma unroll
        for (int k = 0; k < 16; ++k) {
            float wi0 = w_ih[r0 * 16 + k], wi1 = w_ih[r1 * 16 + k];
            float f0 = fc1_w[k * 3 + 0], f1 = fc1_w[k * 3 + 1], f2 = fc1_w[k * 3 + 2];
            float fb = fc1_b[k];
            W00 = fmaf(wi0, f0, W00); W01 = fmaf(wi0, f1, W01); W02 = fmaf(wi0, f2, W02);
            s0  = fmaf(wi0, fb, s0);
            W10 = fmaf(wi1, f0, W10); W11 = fmaf(wi1, f1, W11); W12 = fmaf(wi1, f2, W12);
            s1  = fmaf(wi1, fb, s1);
        }
        bb0 = s0 + b_ih[r0] + b_hh[r0];
        bb1 = s1 + b_ih[r1] + b_hh[r1];
    }
    const float m1 = hi ? 1.0f : 2.0f;   // hi=0: a1 is g -> tanh via sigma(2g)
    float c = 0.f;
    float* hob = h_out + ((size_t)b << 15);
    __syncthreads();

    for (int t = 0; t < S_; ++t) {
        const int rb = (t & 1) << 5;           // read buffer
        const int wb = rb ^ 32;                // write buffer
        float x0 = lds_x[3 * t], x1 = lds_x[3 * t + 1], x2 = lds_x[3 * t + 2];
        float a0 = fmaf(W02, x2, fmaf(W01, x1, fmaf(W00, x0, bb0)));
        float a1 = fmaf(W12, x2, fmaf(W11, x1, fmaf(W10, x0, bb1)));
#pragma unroll
        for (int m = 0; m < 8; ++m) {
            float4 hv = *(const float4*)&lds_h[rb + 4 * m];
            a0 = fmaf(wh0[4*m+0], hv.x, a0); a1 = fmaf(wh1[4*m+0], hv.x, a1);
            a0 = fmaf(wh0[4*m+1], hv.y, a0); a1 = fmaf(wh1[4*m+1], hv.y, a1);
            a0 = fmaf(wh0[4*m+2], hv.z, a0); a1 = fmaf(wh1[4*m+2], hv.z, a1);
            a0 = fmaf(wh0[4*m+3], hv.w, a0); a1 = fmaf(wh1[4*m+3], hv.w, a1);
        }
        // hi=0 lane: s0 = sigma(i), s1 = sigma(2g);  hi=1 lane: s0 = sigma(f), s1 = sigma(o)
        float s0 = sigm(a0);
        float s1 = sigm(a1 * m1);
        float t0 = __shfl_xor(s0, 32);
        float t1 = __shfl_xor(s1, 32);
        float si = hi ? t0 : s0;
        float sf = hi ? s0 : t0;
        float sg = hi ? t1 : s1;               // sigma(2g)
        float so = hi ? s1 : t1;
        float tg = fmaf(2.f, sg, -1.f);        // tanh(g)
        c = fmaf(sf, c, si * tg);
        float tc = fmaf(2.f, sigm(2.f * c), -1.f);  // tanh(c)
        float hval = so * tc;
        if (!hi) {
            lds_h[wb + j] = hval;
            hob[(t << 5) + j] = hval;
        }
        __syncthreads();                        // RAW: next iter reads wb
    }
}

// ---------------- final MLP: out = relu([a1,a2,h]@fc2^T+b2)@fc3^T+b3 ----------------
__global__ __launch_bounds__(256) void final_kernel(
    const float* __restrict__ h,      // (16,1024,32)
    const float* __restrict__ A,      // (2,16,3)
    const float* __restrict__ fc2_w,  // (16,38)
    const float* __restrict__ fc2_b,  // (16,)
    const float* __restrict__ fc3_w,  // (3,16)
    const float* __restrict__ fc3_b,  // (3,)
    float* __restrict__ out)          // (16,1024,3)
{
    __shared__ float sw2[16 * 38], sb2[16], sw3[48], sb3[3], sA[96];
    const int tid = threadIdx.x;
    for (int i = tid; i < 16 * 38; i += 256) sw2[i] = fc2_w[i];
    if (tid < 96) sA[tid] = A[tid];
    if (tid < 16) sb2[tid] = fc2_b[tid];
    if (tid < 48) sw3[tid] = fc3_w[tid];
    if (tid < 3)  sb3[tid] = fc3_b[tid];
    __syncthreads();

    const int p = blockIdx.x * 256 + tid;      // (b<<10)|s
    if (p >= B_ * S_) return;
    const int b = p >> 10;

    float hv[32];
    {
        const float4* hp = (const float4*)(h + ((size_t)p << 5));
#pragma unroll
        for (int m = 0; m < 8; ++m) {
            float4 t = hp[m];
            hv[4*m] = t.x; hv[4*m+1] = t.y; hv[4*m+2] = t.z; hv[4*m+3] = t.w;
        }
    }
    const float a10 = sA[b*3+0], a11 = sA[b*3+1], a12 = sA[b*3+2];
    const float a20 = sA[48+b*3+0], a21 = sA[48+b*3+1], a22 = sA[48+b*3+2];

    float y[16];
#pragma unroll
    for (int u = 0; u < 16; ++u) {
        const float* w = sw2 + u * 38;
        float acc = sb2[u];
        acc = fmaf(w[0], a10, acc); acc = fmaf(w[1], a11, acc); acc = fmaf(w[2], a12, acc);
        acc = fmaf(w[3], a20, acc); acc = fmaf(w[4], a21, acc); acc = fmaf(w[5], a22, acc);
#pragma unroll
        for (int k = 0; k < 32; ++k) acc = fmaf(w[6 + k], hv[k], acc);
        y[u] = fmaxf(acc, 0.f);
    }
#pragma unroll
    for (int d = 0; d < 3; ++d) {
        float o = sb3[d];
#pragma unroll
        for (int u = 0; u < 16; ++u) o = fmaf(sw3[d * 16 + u], y[u], o);
        out[p * 3 + d] = o;
    }
}

extern "C" void kernel_launch(void* const* d_in, const int* in_sizes, int n_in,
                              void* d_out, int out_size, void* d_ws, size_t ws_size,
                              hipStream_t stream) {
    const float* x      = (const float*)d_in[0];
    const float* v1     = (const float*)d_in[1];
    const float* v2     = (const float*)d_in[2];
    const float* attn_w = (const float*)d_in[3];
    // d_in[4] = attn_b: cancels inside softmax, unused
    const float* fc1_w  = (const float*)d_in[5];
    const float* fc1_b  = (const float*)d_in[6];
    const float* w_ih   = (const float*)d_in[7];
    const float* w_hh   = (const float*)d_in[8];
    const float* b_ih   = (const float*)d_in[9];
    const float* b_hh   = (const float*)d_in[10];
    const float* fc2_w  = (const float*)d_in[11];
    const float* fc2_b  = (const float*)d_in[12];
    const float* fc3_w  = (const float*)d_in[13];
    const float* fc3_b  = (const float*)d_in[14];
    float* out = (float*)d_out;

    float* Aws = (float*)d_ws;                         // 2*16*3 floats
    float* hws = (float*)((char*)d_ws + 4096);         // 16*1024*32 floats = 2 MiB

    attn_kernel <<<32, 256, 0, stream>>>(v1, v2, attn_w, Aws);
    lstm_kernel <<<16, 64, 0, stream>>>(x, fc1_w, fc1_b, w_ih, w_hh, b_ih, b_hh, hws);
    final_kernel<<<64, 256, 0, stream>>>(hws, Aws, fc2_w, fc2_b, fc3_w, fc3_b, out);
}

// Round 6
// 395.776 us; speedup vs baseline: 1.0933x; 1.0933x over previous
//
#include <hip/hip_runtime.h>
#include <hip/hip_bf16.h>

#define B_ 16
#define S_ 1024
#define L_ 2048
#define H_ 32

typedef float f2v __attribute__((ext_vector_type(2)));
typedef float f4v __attribute__((ext_vector_type(4)));

// packed dual-FMA (VOP3P v_pk_fma_f32, gfx90a+/gfx950)
static __device__ __forceinline__ f2v pkfma(f2v a, f2v b, f2v c) {
    f2v d;
    asm("v_pk_fma_f32 %0, %1, %2, %3" : "=v"(d) : "v"(a), "v"(b), "v"(c));
    return d;
}
static __device__ __forceinline__ f2v pkadd(f2v a, f2v b) {
    f2v d;
    asm("v_pk_add_f32 %0, %1, %2" : "=v"(d) : "v"(a), "v"(b));
    return d;
}

// ============ fused kernel: blocks 0-15 = LSTM scan, 16-47 = attention ============
__global__ __launch_bounds__(64) void fused_attn_lstm(
    const float* __restrict__ x,      // (16,1024,3)
    const float* __restrict__ v1,     // (16,2049,3)
    const float* __restrict__ v2,
    const float* __restrict__ attn_w, // (1,6)
    const float* __restrict__ fc1_w,  // (16,3)
    const float* __restrict__ fc1_b,  // (16,)
    const float* __restrict__ w_ih,   // (128,16)
    const float* __restrict__ w_hh,   // (128,32)
    const float* __restrict__ b_ih,   // (128,)
    const float* __restrict__ b_hh,   // (128,)
    float* __restrict__ A,            // (2,16,3) ws
    float* __restrict__ h_out)        // (16,1024,32) ws
{
    const int blk = blockIdx.x;
    const int l   = threadIdx.x;

    if (blk >= 16) {
        // ---------------- attention (i-independent softmax over keys) ----------------
        const int idx = blk - 16;
        const int b = idx & 15, sel = idx >> 4;
        const float* v = (sel ? v2 : v1) + (size_t)b * ((L_ + 1) * 3);
        const float wk0 = attn_w[3], wk1 = attn_w[4], wk2 = attn_w[5];

        float s[32];
        float mx = -3.4e38f;
#pragma unroll
        for (int k = 0; k < 32; ++k) {
            const float* p = v + (l + (k << 6)) * 3;      // key rows 0..2047, coalesced
            float sc = fmaf(p[2], wk2, fmaf(p[1], wk1, p[0] * wk0));
            s[k] = sc; mx = fmaxf(mx, sc);
        }
#pragma unroll
        for (int o = 1; o < 64; o <<= 1) mx = fmaxf(mx, __shfl_xor(mx, o));

        float den = 0.f, a0 = 0.f, a1 = 0.f, a2 = 0.f;
#pragma unroll
        for (int k = 0; k < 32; ++k) {
            float e = __expf(s[k] - mx);
            const float* p = v + (l + (k << 6) + 1) * 3;  // value rows 1..2048
            den += e;
            a0 = fmaf(e, p[0], a0); a1 = fmaf(e, p[1], a1); a2 = fmaf(e, p[2], a2);
        }
#pragma unroll
        for (int o = 1; o < 64; o <<= 1) {
            den += __shfl_xor(den, o); a0 += __shfl_xor(a0, o);
            a1  += __shfl_xor(a1, o);  a2 += __shfl_xor(a2, o);
        }
        if (l == 0) {
            float inv = 1.0f / den;
            float* dst = A + sel * 48 + b * 3;
            dst[0] = a0 * inv; dst[1] = a1 * inv; dst[2] = a2 * inv;
        }
        return;
    }

    // ---------------- LSTM scan: one batch per 64-lane wave, NO barriers ----------------
    // lane l: j=l&31, hi=l>>5.  hi=0 -> rows (i_j, g_j); hi=1 -> rows (f_j, o_j)
    const int b  = blk;
    const int j  = l & 31;
    const int hi = l >> 5;
    const int r0 = hi ? (32 + j) : j;          // f : i
    const int r1 = hi ? (96 + j) : (64 + j);   // o : g

    __shared__ float lds_x[S_ * 3];
    __shared__ float lds_h[64];                // double-buffered h

    {   // stage x[b] (12 KiB); single wave -> in-order DS makes later reads safe
        const f4v* src = (const f4v*)(x + (size_t)b * (S_ * 3));
        f4v* dst = (f4v*)lds_x;
#pragma unroll
        for (int m = 0; m < 12; ++m) dst[l + 64 * m] = src[l + 64 * m];
    }
    if (l < 32) lds_h[l] = 0.f;                // buffer 0 = h_{-1}

    // recurrent weight rows, packed as float2 pairs for v_pk_fma_f32
    f2v wh0[16], wh1[16];
    {
        const f4v* p0 = (const f4v*)(w_hh + r0 * H_);
        const f4v* p1 = (const f4v*)(w_hh + r1 * H_);
#pragma unroll
        for (int m = 0; m < 8; ++m) {
            f4v a = p0[m];
            wh0[2*m]   = __builtin_shufflevector(a, a, 0, 1);
            wh0[2*m+1] = __builtin_shufflevector(a, a, 2, 3);
            f4v c2 = p1[m];
            wh1[2*m]   = __builtin_shufflevector(c2, c2, 0, 1);
            wh1[2*m+1] = __builtin_shufflevector(c2, c2, 2, 3);
        }
    }

    // fold fc1 into input path: W = w_ih@fc1_w (2 rows/lane), bb = w_ih@fc1_b + b_ih + b_hh
    float W00 = 0, W01 = 0, W02 = 0, W10 = 0, W11 = 0, W12 = 0, bb0, bb1;
    {
        float s0 = 0, s1 = 0;
#pragma unroll
        for (int k = 0; k < 16; ++k) {
            float wi0 = w_ih[r0 * 16 + k], wi1 = w_ih[r1 * 16 + k];
            float f0 = fc1_w[k * 3 + 0], f1 = fc1_w[k * 3 + 1], f2 = fc1_w[k * 3 + 2];
            float fb = fc1_b[k];
            W00 = fmaf(wi0, f0, W00); W01 = fmaf(wi0, f1, W01); W02 = fmaf(wi0, f2, W02);
            s0  = fmaf(wi0, fb, s0);
            W10 = fmaf(wi1, f0, W10); W11 = fmaf(wi1, f1, W11); W12 = fmaf(wi1, f2, W12);
            s1  = fmaf(wi1, fb, s1);
        }
        bb0 = s0 + b_ih[r0] + b_hh[r0];
        bb1 = s1 + b_ih[r1] + b_hh[r1];
    }

    const float CE = -1.44269504f;             // -log2(e): sigma(x)=rcp(1+exp2(x*CE))
    const float c1 = hi ? CE : 2.f * CE;       // hi=0 lane: a1 is g -> sigma(2g) for tanh
    float c = 0.f;
    float* hob = h_out + ((size_t)b << 15);

    // Per-step recurrent matvec: two independent 8-deep pk-FMA chains per gate
    // (a/b partials) instead of one 16-deep chain -> ~32 fewer dep-cycles/step.
#define STEP(T, RB, WB) do {                                                          \
        float x0 = lds_x[3*(T)], x1 = lds_x[3*(T)+1], x2 = lds_x[3*(T)+2];            \
        f2v acc0a = { fmaf(W02,x2, fmaf(W01,x1, fmaf(W00,x0, bb0))), 0.f };           \
        f2v acc1a = { fmaf(W12,x2, fmaf(W11,x1, fmaf(W10,x0, bb1))), 0.f };           \
        f2v acc0b = { 0.f, 0.f };                                                     \
        f2v acc1b = { 0.f, 0.f };                                                     \
        _Pragma("unroll")                                                             \
        for (int m = 0; m < 8; ++m) {                                                 \
            f4v hv = *(const f4v*)&lds_h[(RB) + 4*m];                                 \
            f2v hlo = __builtin_shufflevector(hv, hv, 0, 1);                          \
            f2v hhi = __builtin_shufflevector(hv, hv, 2, 3);                          \
            acc0a = pkfma(wh0[2*m],   hlo, acc0a);                                    \
            acc1a = pkfma(wh1[2*m],   hlo, acc1a);                                    \
            acc0b = pkfma(wh0[2*m+1], hhi, acc0b);                                    \
            acc1b = pkfma(wh1[2*m+1], hhi, acc1b);                                    \
        }                                                                             \
        f2v acc0 = pkadd(acc0a, acc0b);                                               \
        f2v acc1 = pkadd(acc1a, acc1b);                                               \
        float a0 = acc0.x + acc0.y;                                                   \
        float a1 = acc1.x + acc1.y;                                                   \
        float s0 = __builtin_amdgcn_rcpf(1.f + __builtin_amdgcn_exp2f(a0 * CE));      \
        float s1 = __builtin_amdgcn_rcpf(1.f + __builtin_amdgcn_exp2f(a1 * c1));      \
        float t0 = __shfl_xor(s0, 32);                                                \
        float t1 = __shfl_xor(s1, 32);                                                \
        float si = hi ? t0 : s0;                                                      \
        float sf = hi ? s0 : t0;                                                      \
        float sg = hi ? t1 : s1;                                                      \
        float so = hi ? s1 : t1;                                                      \
        float tg = fmaf(2.f, sg, -1.f);                                               \
        c = fmaf(sf, c, si * tg);                                                     \
        float tc = fmaf(2.f, __builtin_amdgcn_rcpf(1.f + __builtin_amdgcn_exp2f(c * (2.f*CE))), -1.f); \
        float hval = so * tc;                                                         \
        if (!hi) lds_h[(WB) + j] = hval;                                              \
        else     hob[((T) << 5) + j] = hval;                                          \
    } while (0)

    for (int t = 0; t < S_; t += 2) {
        STEP(t,     0, 32);
        STEP(t + 1, 32, 0);
    }
#undef STEP
}

// ---------------- final MLP: out = relu([a1,a2,h]@fc2^T+b2)@fc3^T+b3 ----------------
__global__ __launch_bounds__(256) void final_kernel(
    const float* __restrict__ h,      // (16,1024,32)
    const float* __restrict__ A,      // (2,16,3)
    const float* __restrict__ fc2_w,  // (16,38)
    const float* __restrict__ fc2_b,  // (16,)
    const float* __restrict__ fc3_w,  // (3,16)
    const float* __restrict__ fc3_b,  // (3,)
    float* __restrict__ out)          // (16,1024,3)
{
    __shared__ float sw2[16 * 38], sb2[16], sw3[48], sb3[3], sA[96];
    const int tid = threadIdx.x;
    for (int i = tid; i < 16 * 38; i += 256) sw2[i] = fc2_w[i];
    if (tid < 96) sA[tid] = A[tid];
    if (tid < 16) sb2[tid] = fc2_b[tid];
    if (tid < 48) sw3[tid] = fc3_w[tid];
    if (tid < 3)  sb3[tid] = fc3_b[tid];
    __syncthreads();

    const int p = blockIdx.x * 256 + tid;      // (b<<10)|s
    if (p >= B_ * S_) return;
    const int b = p >> 10;

    float hv[32];
    {
        const float4* hp = (const float4*)(h + ((size_t)p << 5));
#pragma unroll
        for (int m = 0; m < 8; ++m) {
            float4 t = hp[m];
            hv[4*m] = t.x; hv[4*m+1] = t.y; hv[4*m+2] = t.z; hv[4*m+3] = t.w;
        }
    }
    const float a10 = sA[b*3+0], a11 = sA[b*3+1], a12 = sA[b*3+2];
    const float a20 = sA[48+b*3+0], a21 = sA[48+b*3+1], a22 = sA[48+b*3+2];

    float y[16];
#pragma unroll
    for (int u = 0; u < 16; ++u) {
        const float* w = sw2 + u * 38;
        float acc = sb2[u];
        acc = fmaf(w[0], a10, acc); acc = fmaf(w[1], a11, acc); acc = fmaf(w[2], a12, acc);
        acc = fmaf(w[3], a20, acc); acc = fmaf(w[4], a21, acc); acc = fmaf(w[5], a22, acc);
#pragma unroll
        for (int k = 0; k < 32; ++k) acc = fmaf(w[6 + k], hv[k], acc);
        y[u] = fmaxf(acc, 0.f);
    }
#pragma unroll
    for (int d = 0; d < 3; ++d) {
        float o = sb3[d];
#pragma unroll
        for (int u = 0; u < 16; ++u) o = fmaf(sw3[d * 16 + u], y[u], o);
        out[p * 3 + d] = o;
    }
}

extern "C" void kernel_launch(void* const* d_in, const int* in_sizes, int n_in,
                              void* d_out, int out_size, void* d_ws, size_t ws_size,
                              hipStream_t stream) {
    const float* x      = (const float*)d_in[0];
    const float* v1     = (const float*)d_in[1];
    const float* v2     = (const float*)d_in[2];
    const float* attn_w = (const float*)d_in[3];
    // d_in[4] = attn_b: shift-invariant under softmax, unused
    const float* fc1_w  = (const float*)d_in[5];
    const float* fc1_b  = (const float*)d_in[6];
    const float* w_ih   = (const float*)d_in[7];
    const float* w_hh   = (const float*)d_in[8];
    const float* b_ih   = (const float*)d_in[9];
    const float* b_hh   = (const float*)d_in[10];
    const float* fc2_w  = (const float*)d_in[11];
    const float* fc2_b  = (const float*)d_in[12];
    const float* fc3_w  = (const float*)d_in[13];
    const float* fc3_b  = (const float*)d_in[14];
    float* out = (float*)d_out;

    float* Aws = (float*)d_ws;                         // 2*16*3 floats
    float* hws = (float*)((char*)d_ws + 4096);         // 16*1024*32 floats = 2 MiB

    fused_attn_lstm<<<48, 64, 0, stream>>>(x, v1, v2, attn_w, fc1_w, fc1_b,
                                           w_ih, w_hh, b_ih, b_hh, Aws, hws);
    final_kernel  <<<64, 256, 0, stream>>>(hws, Aws, fc2_w, fc2_b, fc3_w, fc3_b, out);
}